// Round 3
// baseline (1142.040 us; speedup 1.0000x reference)
//
#include <hip/hip_runtime.h>
#include <hip/hip_bf16.h>
#include <stdint.h>

// ---------------------------------------------------------------------------
// DeepseekV2 decoder layer, bf16 MFMA path, round 6.
// R5 post-mortem: schedule surgery moved MfmaUtil only 38->40%. Real limit:
// 64x64 wave tiles read 0.75 (gup) / 0.5 (p2) LDS-b128 per MFMA -> LDS read
// traffic >= matrix time. Fix: m201 geometry everywhere — 256x256 block,
// BK=64, 8 waves (2Mx4N, 16-row interleave), 128x64 wave tile = 0.375
// reads/MFMA. gate/up de-fused (up writes u bf16; gate epilogue does
// silu(g_f32)*u). q/o/down split-K=2 so grid = 256 blocks (1/CU) + fp32
// partial combine passes. One counted vmcnt(2) gate per K-tile.
// ---------------------------------------------------------------------------

typedef __bf16 bf16;
typedef bf16 bf16x8 __attribute__((ext_vector_type(8)));
typedef bf16 bf16x4 __attribute__((ext_vector_type(4)));
typedef float f32x4 __attribute__((ext_vector_type(4)));

#define HID     2048
#define TOK     4096
#define INTER   10944
#define INTER_P 11008   // padded to multiple of 256; pad region is zeros

__device__ __forceinline__ void gload_lds16(const bf16* g, bf16* l) {
    __builtin_amdgcn_global_load_lds(
        (const __attribute__((address_space(1))) void*)g,
        (__attribute__((address_space(3))) void*)l, 16, 0, 0);
}

#define SBAR()      asm volatile("s_barrier" ::: "memory")
#define VMCNT(n)    asm volatile("s_waitcnt vmcnt(" #n ")" ::: "memory")
#define LGKM(n)     asm volatile("s_waitcnt lgkmcnt(" #n ")" ::: "memory")
#define SCHED0()    __builtin_amdgcn_sched_barrier(0)
#define PRIO(n)     __builtin_amdgcn_s_setprio(n)
#define FMA16(d, a, b) d = __builtin_amdgcn_mfma_f32_16x16x32_bf16(a, b, d, 0, 0, 0)

// ---------------------------------------------------------------------------
// fp32 -> bf16 conversion with zero tail (row padding for Wg/Wu).
// ---------------------------------------------------------------------------
__global__ __launch_bounds__(256) void conv_pad(const float* __restrict__ src,
                                                bf16* __restrict__ dst,
                                                int n_src, int n_dst) {
    int i = (blockIdx.x * 256 + threadIdx.x) * 4;
    if (i >= n_dst) return;
    float4 v = make_float4(0.f, 0.f, 0.f, 0.f);
    if (i < n_src) v = *(const float4*)(src + i);
    bf16x4 o;
    o[0] = (bf16)v.x; o[1] = (bf16)v.y; o[2] = (bf16)v.z; o[3] = (bf16)v.w;
    *(bf16x4*)(dst + i) = o;
}

// Wd [2048,10944] -> [2048,11008], columns padded with zeros.
__global__ __launch_bounds__(256) void conv_wd(const float* __restrict__ src,
                                               bf16* __restrict__ dst) {
    int i = (blockIdx.x * 256 + threadIdx.x) * 4;
    if (i >= HID * INTER_P) return;
    int row = i / INTER_P;
    int col = i - row * INTER_P;
    float4 v = make_float4(0.f, 0.f, 0.f, 0.f);
    if (col < INTER)
        v = *(const float4*)(src + (size_t)row * INTER + col);
    bf16x4 o;
    o[0] = (bf16)v.x; o[1] = (bf16)v.y; o[2] = (bf16)v.z; o[3] = (bf16)v.w;
    *(bf16x4*)(dst + i) = o;
}

// ---------------------------------------------------------------------------
// RMSNorm: one block per row of 2048 fp32, emit bf16 * w.
// ---------------------------------------------------------------------------
__global__ __launch_bounds__(256) void rmsnorm_k(const float* __restrict__ x,
                                                 const float* __restrict__ w,
                                                 bf16* __restrict__ out) {
    const int row = blockIdx.x;
    const int tid = threadIdx.x;
    const float* xr = x + (size_t)row * HID + tid * 8;
    float4 v0 = *(const float4*)(xr);
    float4 v1 = *(const float4*)(xr + 4);
    float s = v0.x * v0.x + v0.y * v0.y + v0.z * v0.z + v0.w * v0.w +
              v1.x * v1.x + v1.y * v1.y + v1.z * v1.z + v1.w * v1.w;
    #pragma unroll
    for (int o = 32; o > 0; o >>= 1) s += __shfl_down(s, o);
    __shared__ float red[4];
    if ((tid & 63) == 0) red[tid >> 6] = s;
    __syncthreads();
    float tot = red[0] + red[1] + red[2] + red[3];
    float scale = rsqrtf(tot * (1.0f / (float)HID) + 1e-6f);
    float4 w0 = *(const float4*)(w + tid * 8);
    float4 w1 = *(const float4*)(w + tid * 8 + 4);
    bf16x8 o8;
    o8[0] = (bf16)(v0.x * scale * w0.x);
    o8[1] = (bf16)(v0.y * scale * w0.y);
    o8[2] = (bf16)(v0.z * scale * w0.z);
    o8[3] = (bf16)(v0.w * scale * w0.w);
    o8[4] = (bf16)(v1.x * scale * w1.x);
    o8[5] = (bf16)(v1.y * scale * w1.y);
    o8[6] = (bf16)(v1.z * scale * w1.z);
    o8[7] = (bf16)(v1.w * scale * w1.w);
    *(bf16x8*)(out + (size_t)row * HID + tid * 8) = o8;
}

// ---------------------------------------------------------------------------
// m201-geometry GEMM: C[M,N] = A[M,K] * W[N,K]^T over K-range z.
// 256x256 block tile, BK=64, 512 thr = 8 waves (2M x 4N), wave = 128x64.
// Wave rows interleaved at 16: A row = mi*32 + wm*16 + fr; W row =
// nj*64 + wn*16 + fr -> each quadrant phase reads exactly one A/W half-tile
// across ALL waves. 2 LDS buffers x 64KB (A 32K + W 32K).
// Per K-tile: 4 phases (quadrants 00,01,11,10), 16 MFMA each.
// Staging stream: one half-tile pair (2 x global_load_lds) per phase:
//   P0: W0(t+1)  P1: A1(t+1)  P2: W1(t+1)  P3: A0(t+2)
// Single gate per tile at P3: vmcnt(2) leaves only this phase's pair in
// flight -> everything tile t+1 reads is landed. Raw barriers; counted
// waits only (drain only in the 2-tile tail).
// EPI 0: fp32 partial -> (z ? out1 : out0).  EPI 1: bf16 store.
// EPI 2: read u=out0[idx] (bf16), store bf16(silu(acc)*u).
// ---------------------------------------------------------------------------
#define BUFE 32768   // elems per buffer (64KB): A [256][64] + W [256][64]

template <int EPI>
__global__ __launch_bounds__(512, 2) void gemm256(const bf16* __restrict__ A,
                                                  const bf16* __restrict__ W,
                                                  float* __restrict__ out0,
                                                  float* __restrict__ out1,
                                                  int N, int K, int ntz) {
    extern __shared__ bf16 lds[];
    const int tid = threadIdx.x;
    const int rowBase = blockIdx.x * 256;   // M fastest: weight-panel locality
    const int colBase = blockIdx.y * 256;
    const int kt0 = blockIdx.z * ntz;
    const int wave = tid >> 6, lane = tid & 63;
    const int wm = wave >> 2, wn = wave & 3;   // 2 M-waves x 4 N-waves
    const int fr = lane & 15, kq = lane >> 4;

    // staging: pass = 64 rows x 64 cols; thread -> row tid>>3, chunk tid&7;
    // source chunk pre-swizzled so linear LDS dest == swizzled layout.
    const int slr = tid >> 3;
    const int sc  = (tid & 7) ^ (slr & 7);
    const bf16* sAb = A + (size_t)(rowBase + slr) * K + sc * 8;
    const bf16* sWb = W + (size_t)(colBase + slr) * K + sc * 8;
    const int ldst = tid * 8;

    // fragment offsets: row r, data chunk d=ks*4+kq stored at chunk d^(r&7)
    int aof[8][2], wof[4][2];
    #pragma unroll
    for (int mi = 0; mi < 8; ++mi) {
        const int ra = mi * 32 + wm * 16 + fr;
        #pragma unroll
        for (int ks = 0; ks < 2; ++ks)
            aof[mi][ks] = ra * 64 + (((ks * 4 + kq) ^ (ra & 7)) * 8);
    }
    #pragma unroll
    for (int nj = 0; nj < 4; ++nj) {
        const int rw = nj * 64 + wn * 16 + fr;
        #pragma unroll
        for (int ks = 0; ks < 2; ++ks)
            wof[nj][ks] = 16384 + rw * 64 + (((ks * 4 + kq) ^ (rw & 7)) * 8);
    }

    f32x4 acc[8][4] = {};

    // stage one half-tile pair: isA selects matrix, hh = half (128 rows)
#define STG(isA, hh, tt)                                                     \
    do {                                                                     \
        const bf16* _b = (isA) ? sAb : sWb;                                  \
        bf16* _d = &lds[(((tt) & 1) * BUFE) + ((isA) ? 0 : 16384) +          \
                        (hh) * 8192 + ldst];                                 \
        const size_t _kb = (size_t)(kt0 + (tt)) * 64;                        \
        gload_lds16(_b + (size_t)((hh) * 128) * K + _kb, _d);                \
        gload_lds16(_b + (size_t)((hh) * 128 + 64) * K + _kb, _d + 4096);    \
    } while (0)

    // prologue: T0 {A0,W0,A1,W1} + T1.A0 (5 pairs); gate leaves T1.A0 pair
    STG(1, 0, 0); STG(0, 0, 0); STG(1, 1, 0); STG(0, 1, 0);
    STG(1, 0, 1);
    VMCNT(2);
    SBAR();

    for (int t = 0; t < ntz; ++t) {
        const int bb = (t & 1) * BUFE;
        const bool s1 = (t + 1) < ntz;
        const bool s2 = (t + 2) < ntz;
        bf16x8 aF[4][2], wF0[2][2], wF1[2][2];
        // ---- P0: quad (h0,v0); stage W0(t+1); read A0 (8) + W0 (4)
        if (s1) STG(0, 0, t + 1);
        #pragma unroll
        for (int m = 0; m < 4; ++m)
          #pragma unroll
          for (int ks = 0; ks < 2; ++ks)
            aF[m][ks] = *(const bf16x8*)&lds[bb + aof[m][ks]];
        #pragma unroll
        for (int n = 0; n < 2; ++n)
          #pragma unroll
          for (int ks = 0; ks < 2; ++ks)
            wF0[n][ks] = *(const bf16x8*)&lds[bb + wof[n][ks]];
        LGKM(8);
        SBAR(); LGKM(0); SCHED0();
        PRIO(1);
        #pragma unroll
        for (int ks = 0; ks < 2; ++ks)
          #pragma unroll
          for (int m = 0; m < 4; ++m)
            #pragma unroll
            for (int n = 0; n < 2; ++n)
                FMA16(acc[m][n], aF[m][ks], wF0[n][ks]);
        PRIO(0); SCHED0(); SBAR();
        // ---- P1: quad (h0,v1); stage A1(t+1); read W1 (4)
        if (s1) STG(1, 1, t + 1);
        #pragma unroll
        for (int n = 0; n < 2; ++n)
          #pragma unroll
          for (int ks = 0; ks < 2; ++ks)
            wF1[n][ks] = *(const bf16x8*)&lds[bb + wof[2 + n][ks]];
        SBAR(); LGKM(0); SCHED0();
        PRIO(1);
        #pragma unroll
        for (int ks = 0; ks < 2; ++ks)
          #pragma unroll
          for (int m = 0; m < 4; ++m)
            #pragma unroll
            for (int n = 0; n < 2; ++n)
                FMA16(acc[m][2 + n], aF[m][ks], wF1[n][ks]);
        PRIO(0); SCHED0(); SBAR();
        // ---- P2: quad (h1,v1); stage W1(t+1); read A1 (8, overwrite aF)
        if (s1) STG(0, 1, t + 1);
        #pragma unroll
        for (int m = 0; m < 4; ++m)
          #pragma unroll
          for (int ks = 0; ks < 2; ++ks)
            aF[m][ks] = *(const bf16x8*)&lds[bb + aof[4 + m][ks]];
        SBAR(); LGKM(0); SCHED0();
        PRIO(1);
        #pragma unroll
        for (int ks = 0; ks < 2; ++ks)
          #pragma unroll
          for (int m = 0; m < 4; ++m)
            #pragma unroll
            for (int n = 0; n < 2; ++n)
                FMA16(acc[4 + m][2 + n], aF[m][ks], wF1[n][ks]);
        PRIO(0); SCHED0(); SBAR();
        // ---- P3: quad (h1,v0); stage A0(t+2); no reads (aF from P2, wF0 P0)
        if (s2) STG(1, 0, t + 2);
        SCHED0();
        PRIO(1);
        #pragma unroll
        for (int ks = 0; ks < 2; ++ks)
          #pragma unroll
          for (int m = 0; m < 4; ++m)
            #pragma unroll
            for (int n = 0; n < 2; ++n)
                FMA16(acc[4 + m][n], aF[m][ks], wF0[n][ks]);
        PRIO(0); SCHED0();
        // gate: everything tile t+1 reads has landed; only this phase's
        // pair may stay in flight
        if (s2) VMCNT(2); else VMCNT(0);
        SBAR();
    }
#undef STG
    // C/D layout: col = lane&15, row = (lane>>4)*4 + reg  [m89/m91]
    const int rq = lane >> 4, cn = lane & 15;
    float* dst = blockIdx.z ? out1 : out0;
    #pragma unroll
    for (int mi = 0; mi < 8; ++mi)
      #pragma unroll
      for (int nj = 0; nj < 4; ++nj) {
        const int col = colBase + nj * 64 + wn * 16 + cn;
        #pragma unroll
        for (int r = 0; r < 4; ++r) {
            const int row = rowBase + mi * 32 + wm * 16 + rq * 4 + r;
            const size_t idx = (size_t)row * N + col;
            const float v = acc[mi][nj][r];
            if (EPI == 0) {
                dst[idx] = v;
            } else if (EPI == 1) {
                ((bf16*)out0)[idx] = (bf16)v;
            } else {
                bf16* p = (bf16*)out0;
                const float u = (float)p[idx];
                const float sg = v / (1.0f + __expf(-v));   // silu, fp32 g
                p[idx] = (bf16)(sg * u);
            }
        }
      }
}

// ---------------------------------------------------------------------------
// Split-K combine: out = p0 + p1 (+ res). MODE 0: bf16 out. MODE 1: fp32 out.
// ---------------------------------------------------------------------------
template <int MODE>
__global__ __launch_bounds__(256) void combine_k(const float* __restrict__ p0,
                                                 const float* __restrict__ p1,
                                                 const float* __restrict__ res,
                                                 void* __restrict__ out, int n) {
    for (int i = (blockIdx.x * 256 + threadIdx.x) * 4; i < n;
         i += gridDim.x * 1024) {
        float4 a = *(const float4*)(p0 + i);
        float4 b = *(const float4*)(p1 + i);
        float4 v = make_float4(a.x + b.x, a.y + b.y, a.z + b.z, a.w + b.w);
        if (MODE == 1) {
            float4 r = *(const float4*)(res + i);
            v.x += r.x; v.y += r.y; v.z += r.z; v.w += r.w;
            *(float4*)((float*)out + i) = v;
        } else {
            bf16x4 o;
            o[0] = (bf16)v.x; o[1] = (bf16)v.y;
            o[2] = (bf16)v.z; o[3] = (bf16)v.w;
            *(bf16x4*)((bf16*)out + i) = o;
        }
    }
}

// ---------------------------------------------------------------------------
extern "C" void kernel_launch(void* const* d_in, const int* in_sizes, int n_in,
                              void* d_out, int out_size, void* d_ws, size_t ws_size,
                              hipStream_t stream) {
    const float* x      = (const float*)d_in[0];
    const float* in_w   = (const float*)d_in[2];
    const float* post_w = (const float*)d_in[3];
    const float* Wq     = (const float*)d_in[4];
    const float* Wo     = (const float*)d_in[5];
    const float* Wg     = (const float*)d_in[6];
    const float* Wu     = (const float*)d_in[7];
    const float* Wd     = (const float*)d_in[8];

    // >64KB dynamic LDS needs the opt-in attribute (host-side, capture-safe).
    const int LDSB = 2 * BUFE * 2;   // 128KB
    hipFuncSetAttribute(reinterpret_cast<const void*>(&gemm256<0>),
                        hipFuncAttributeMaxDynamicSharedMemorySize, LDSB);
    hipFuncSetAttribute(reinterpret_cast<const void*>(&gemm256<1>),
                        hipFuncAttributeMaxDynamicSharedMemorySize, LDSB);
    hipFuncSetAttribute(reinterpret_cast<const void*>(&gemm256<2>),
                        hipFuncAttributeMaxDynamicSharedMemorySize, LDSB);

    char* ws = (char*)d_ws;
    bf16*  X    = (bf16*)(ws + 0);           // 16.8MB: h_norm, later h_post
    bf16*  Yq   = (bf16*)(ws + 16777216);    // 16.8MB: q (bf16)
    float* hid  = (float*)(ws + 33554432);   // 33.6MB: hidden (fp32 residual)
    bf16*  gu   = (bf16*)(ws + 67108864);    // 45.1MB: u, then silu(g)*u
    bf16*  w0   = (bf16*)(ws + 157286400);   // 45.1MB: Wg bf16, later Wd bf16
    bf16*  w1   = (bf16*)(ws + 202375168);   // 45.1MB: Wu bf16
    bf16*  wsm  = (bf16*)(ws + 247463936);   // 8.4MB : Wq bf16, later Wo bf16
    // split-K partial slabs (33.55MB each), time-multiplexed:
    float* qp0  = (float*)(ws + 67108864);   // in gu slab (free pre-MLP)
    float* qp1  = (float*)(ws + 100663296);
    float* dp0  = (float*)(ws + 202375168);  // w1 slab (Wu dead after gate)
    float* dp1  = (float*)(ws + 0);          // X+Yq slabs (dead after gate)

    const int nGU  = INTER_P * HID;
    const int nGUs = INTER * HID;
    const int nSq  = HID * HID;
    const int nTH  = TOK * HID;              // 8.4M output elems

    conv_pad<<<nGU / 4 / 256, 256, 0, stream>>>(Wg, w0, nGUs, nGU);
    conv_pad<<<nGU / 4 / 256, 256, 0, stream>>>(Wu, w1, nGUs, nGU);
    conv_pad<<<nSq / 4 / 256, 256, 0, stream>>>(Wq, wsm, nSq, nSq);

    rmsnorm_k<<<TOK, 256, 0, stream>>>(x, in_w, X);
    // q = h_norm @ Wq^T  (split-K=2: 16x8x2 = 256 blocks, 1/CU)
    gemm256<0><<<dim3(TOK / 256, HID / 256, 2), 512, LDSB, stream>>>(
        X, wsm, qp0, qp1, HID, HID, 16);
    combine_k<0><<<2048, 256, 0, stream>>>(qp0, qp1, nullptr, Yq, nTH);
    conv_pad<<<nSq / 4 / 256, 256, 0, stream>>>(Wo, wsm, nSq, nSq);
    // hidden = x + q @ Wo^T
    gemm256<0><<<dim3(TOK / 256, HID / 256, 2), 512, LDSB, stream>>>(
        Yq, wsm, qp0, qp1, HID, HID, 16);
    combine_k<1><<<2048, 256, 0, stream>>>(qp0, qp1, x, hid, nTH);
    rmsnorm_k<<<TOK, 256, 0, stream>>>(hid, post_w, X);
    // u = h_post @ Wu^T  (bf16 into gu slab)
    gemm256<1><<<dim3(TOK / 256, INTER_P / 256, 1), 512, LDSB, stream>>>(
        X, w1, (float*)gu, nullptr, INTER_P, HID, 32);
    // gu = silu(h_post @ Wg^T) * u  (epilogue reads+overwrites gu)
    gemm256<2><<<dim3(TOK / 256, INTER_P / 256, 1), 512, LDSB, stream>>>(
        X, w0, (float*)gu, nullptr, INTER_P, HID, 32);
    conv_wd<<<nGU / 4 / 256, 256, 0, stream>>>(Wd, w0);
    // down partials: split-K=2 over K=11008
    gemm256<0><<<dim3(TOK / 256, HID / 256, 2), 512, LDSB, stream>>>(
        gu, w0, dp0, dp1, HID, INTER_P, 86);
    // out = hidden + dp0 + dp1
    combine_k<1><<<2048, 256, 0, stream>>>(dp0, dp1, hid, (float*)d_out, nTH);
}